// Round 3
// baseline (368.857 us; speedup 1.0000x reference)
//
#include <hip/hip_runtime.h>

// EncoderBlock: pre-LN MHSA + pre-LN GELU FFN.  S=2048 D=1024 H=16 DK=64 MLP=4096.
// GEMMs: bf16 MFMA 16x16x32, 128x128 tile, XOR-swizzled LDS, split-K for N=1024.
// Attention: flash, KV-split x2, register-prefetch double-buffered staging,
// Ps stride 140 (conflict-free b16 writes), Ps aliases dead Q region (3 blk/CU).

constexpr int kS = 2048, kD = 1024, kH = 16, kDK = 64, kMLP = 4096;
constexpr float kEps = 1e-5f;

using u16 = unsigned short;
using u32 = unsigned int;
typedef float f32x4 __attribute__((ext_vector_type(4)));
typedef short bf16x8 __attribute__((ext_vector_type(8)));   // 8 bf16 = 4 VGPRs

__device__ __forceinline__ u16 f2b(float f) {               // fp32 -> bf16 (RNE)
  u32 u = __builtin_bit_cast(u32, f);
  return (u16)((u + 0x7fffu + ((u >> 16) & 1u)) >> 16);
}

typedef const __attribute__((address_space(1))) u32* gas1;
typedef __attribute__((address_space(3))) u32* las3;
__device__ __forceinline__ void async16(const void* g, void* l) {
  __builtin_amdgcn_global_load_lds((gas1)g, (las3)l, 16, 0, 0);
}

// ---------------- LayerNorm: fp32 [row][1024] -> bf16 ----------------
__global__ __launch_bounds__(256)
void ln_kernel(const float* __restrict__ x, const float* __restrict__ g,
               const float* __restrict__ b, u16* __restrict__ out) {
  __shared__ float red[8];
  const int row = blockIdx.x, tid = threadIdx.x;
  const float4 v = *(const float4*)(x + (size_t)row * kD + tid * 4);
  float s = v.x + v.y + v.z + v.w;
  float ss = v.x * v.x + v.y * v.y + v.z * v.z + v.w * v.w;
#pragma unroll
  for (int d = 1; d < 64; d <<= 1) { s += __shfl_xor(s, d); ss += __shfl_xor(ss, d); }
  if ((tid & 63) == 0) { red[tid >> 6] = s; red[4 + (tid >> 6)] = ss; }
  __syncthreads();
  const float m = (red[0] + red[1] + red[2] + red[3]) * (1.f / kD);
  const float var = (red[4] + red[5] + red[6] + red[7]) * (1.f / kD) - m * m;
  const float r = rsqrtf(var + kEps);
  const float4 gv = *(const float4*)(g + tid * 4);
  const float4 bv = *(const float4*)(b + tid * 4);
  ushort4 o;
  o.x = f2b((v.x - m) * r * gv.x + bv.x);
  o.y = f2b((v.y - m) * r * gv.y + bv.y);
  o.z = f2b((v.z - m) * r * gv.z + bv.z);
  o.w = f2b((v.w - m) * r * gv.w + bv.w);
  *(ushort4*)(out + (size_t)row * kD + tid * 4) = o;
}

// ------------- transpose + fp32->bf16:  out[c][r] = in[r][c] -------------
__global__ __launch_bounds__(256)
void transpose_cvt(const float* __restrict__ in, u16* __restrict__ out, int R, int C) {
  __shared__ float tile[32][33];
  const int c0 = blockIdx.x * 32, r0 = blockIdx.y * 32;
  const int x = threadIdx.x, y = threadIdx.y;
#pragma unroll
  for (int i = 0; i < 4; ++i)
    tile[y + i * 8][x] = in[(size_t)(r0 + y + i * 8) * C + c0 + x];
  __syncthreads();
#pragma unroll
  for (int i = 0; i < 4; ++i)
    out[(size_t)(c0 + y + i * 8) * R + r0 + x] = f2b(tile[x][y + i * 8]);
}

__global__ void concat_bias(const float* __restrict__ bq, const float* __restrict__ bk,
                            const float* __restrict__ bv, float* __restrict__ out) {
  int i = blockIdx.x * 256 + threadIdx.x;  // 3072
  out[i] = i < kD ? bq[i] : (i < 2 * kD ? bk[i - kD] : bv[i - 2 * kD]);
}

// --- per-head V transpose: qkv[s][2048+h*64+d] (bf16) -> vt[h][d][s] (bf16) ---
__global__ __launch_bounds__(256)
void vtrans(const u16* __restrict__ qkv, u16* __restrict__ vt) {
  __shared__ u16 t[64][72];
  const int s0 = blockIdx.x * 64, h = blockIdx.y, tid = threadIdx.x;
#pragma unroll
  for (int r = 0; r < 2; ++r) {
    int chunk = r * 256 + tid, row = chunk >> 3, col = (chunk & 7) * 8;
    uint4 v = *(const uint4*)(qkv + (size_t)(s0 + row) * 3072 + 2 * kD + h * 64 + col);
    *(uint4*)(&t[row][col]) = v;
  }
  __syncthreads();
#pragma unroll
  for (int r = 0; r < 2; ++r) {
    int chunk = r * 256 + tid, drow = chunk >> 3, scol = (chunk & 7) * 8;
    u16 tmp[8];
#pragma unroll
    for (int j = 0; j < 8; ++j) tmp[j] = t[scol + j][drow];
    *(uint4*)(vt + (size_t)h * 64 * kS + (size_t)drow * kS + s0 + scol) = *(uint4*)tmp;
  }
}

// ---------------- bt-GEMM: C[M,N] = A[M,K](bf16) x Bt[N,K](bf16) ----------------
// EPI 0: bf16 out (+bias)  EPI 1: bf16 gelu_erf out (+bias)  EPI 3: fp32 split-K partial
template <int EPI>
__global__ __launch_bounds__(256, 2)
void gemm_bt(const u16* __restrict__ A, const u16* __restrict__ Bt,
             const float* __restrict__ bias, void* __restrict__ Cout,
             int N, int K, int Ksub) {
  constexpr int BM = 128, BN = 128, BK = 32;
  constexpr int MT = 4, NT = 4;
  __shared__ u16 As[BM * BK];
  __shared__ u16 Bs[BN * BK];
  const int tid = threadIdx.x;
  const int w = tid >> 6, l = tid & 63;
  const int wm = w >> 1, wn = w & 1;
  const int row0 = blockIdx.y * BM, col0 = blockIdx.x * BN;
  const int koff = blockIdx.z * Ksub;

  const int sc = ((l & 3) ^ ((l >> 3) & 3)) * 8;   // XOR-swizzled staging chunk
  const u16* Ag = A + (size_t)(row0 + w * 16 + (l >> 2)) * K + koff + sc;
  const u16* Bg = Bt + (size_t)(col0 + w * 16 + (l >> 2)) * K + koff + sc;
  u16* AsW = As + w * 512;
  u16* BsW = Bs + w * 512;

  f32x4 acc[MT][NT] = {};
  const int q = l >> 4;

  for (int kt = 0; kt < Ksub; kt += BK) {
#pragma unroll
    for (int r = 0; r < 2; ++r) async16(Ag + (size_t)r * 64 * K + kt, AsW + r * 2048);
#pragma unroll
    for (int r = 0; r < 2; ++r) async16(Bg + (size_t)r * 64 * K + kt, BsW + r * 2048);
    __syncthreads();
    bf16x8 af[MT], bfr[NT];
#pragma unroll
    for (int i = 0; i < MT; ++i) {
      const int ra = wm * 64 + i * 16 + (l & 15);
      af[i] = *(const bf16x8*)(As + ra * 32 + (q ^ ((ra >> 1) & 3)) * 8);
    }
#pragma unroll
    for (int j = 0; j < NT; ++j) {
      const int rb = wn * 64 + j * 16 + (l & 15);
      bfr[j] = *(const bf16x8*)(Bs + rb * 32 + (q ^ ((rb >> 1) & 3)) * 8);
    }
#pragma unroll
    for (int i = 0; i < MT; ++i)
#pragma unroll
      for (int j = 0; j < NT; ++j)
        acc[i][j] = __builtin_amdgcn_mfma_f32_16x16x32_bf16(af[i], bfr[j], acc[i][j], 0, 0, 0);
    __syncthreads();
  }

  float* Pf = nullptr;
  if constexpr (EPI == 3)
    Pf = (float*)Cout + (size_t)blockIdx.z * gridDim.y * BM * N;
#pragma unroll
  for (int i = 0; i < MT; ++i) {
    const int row = row0 + wm * 64 + i * 16 + ((l >> 4) << 2);
#pragma unroll
    for (int j = 0; j < NT; ++j) {
      const int col = col0 + wn * 64 + j * 16 + (l & 15);
      float bb = 0.f;
      if constexpr (EPI != 3) bb = bias[col];
#pragma unroll
      for (int r = 0; r < 4; ++r) {
        const size_t idx = (size_t)(row + r) * N + col;
        float v = acc[i][j][r] + bb;
        if constexpr (EPI == 0) {
          ((u16*)Cout)[idx] = f2b(v);
        } else if constexpr (EPI == 1) {
          ((u16*)Cout)[idx] = f2b(0.5f * v * (1.f + erff(v * 0.7071067811865475f)));
        } else {
          Pf[idx] = v;
        }
      }
    }
  }
}

// ---- split-K reduce: out = sum_s parts[s] + bias + res  (fp32, float4) ----
template <int KS>
__global__ __launch_bounds__(256)
void reduce_add(const float* __restrict__ parts, const float* __restrict__ bias,
                const float* __restrict__ res, float* __restrict__ out,
                int N, size_t strideMN) {
  const size_t b = ((size_t)blockIdx.x * 256 + threadIdx.x) * 4;
  float4 a = *(const float4*)(res + b);
  const float4 bv = *(const float4*)(bias + (b & (size_t)(N - 1)));
  a.x += bv.x; a.y += bv.y; a.z += bv.z; a.w += bv.w;
#pragma unroll
  for (int s = 0; s < KS; ++s) {
    const float4 p = *(const float4*)(parts + s * strideMN + b);
    a.x += p.x; a.y += p.y; a.z += p.z; a.w += p.w;
  }
  *(float4*)(out + b) = a;
}

// ---------------- flash attention (KV-split x2, double-buffered) ----------------
// grid (S/64, H, 2); 4 waves; wave w owns q-rows [q0+w*16,+16).  Each block does
// 8 K-tiles of 128 keys.  Outputs UNNORMALIZED O (fp32) + (m,l) per row.
__global__ __launch_bounds__(256, 3)
void flash_attn(const u16* __restrict__ qkv, const u16* __restrict__ vt,
                float* __restrict__ Op, float* __restrict__ Ml) {
  constexpr int LQ = 72;    // Q/K row stride (u16)
  constexpr int LV = 136;   // V^T row stride
  constexpr int LP = 140;   // Ps row stride: quad starts {0,24,16,8} -> conflict-free
  __shared__ u16 PsQ[4 * 16 * LP];   // Ps regions; Q staged here in prologue (dead after)
  __shared__ u16 Ks[128 * LQ];
  __shared__ u16 Vs[64 * LV];
  const int tid = threadIdx.x, w = tid >> 6, l = tid & 63;
  const int h = blockIdx.y, q0 = blockIdx.x * 64, z = blockIdx.z;
  const int kt0 = z * (kS / 2);

  const u16* Kg = qkv + kD + h * 64;
  const u16* Vg = vt + (size_t)h * 64 * kS;

  uint4 kreg[4], vreg[4];
  auto load_tile = [&](int kt) {
#pragma unroll
    for (int r = 0; r < 4; ++r) {
      int c = r * 256 + tid;
      kreg[r] = *(const uint4*)(Kg + (size_t)(kt + (c >> 3)) * 3072 + (c & 7) * 8);
    }
#pragma unroll
    for (int r = 0; r < 4; ++r) {
      int c = r * 256 + tid;
      vreg[r] = *(const uint4*)(Vg + (size_t)(c >> 4) * kS + kt + (c & 15) * 8);
    }
  };
  auto store_tile = [&]() {
#pragma unroll
    for (int r = 0; r < 4; ++r) {
      int c = r * 256 + tid;
      *(uint4*)(&Ks[(c >> 3) * LQ + (c & 7) * 8]) = kreg[r];
    }
#pragma unroll
    for (int r = 0; r < 4; ++r) {
      int c = r * 256 + tid;
      *(uint4*)(&Vs[(c >> 4) * LV + (c & 15) * 8]) = vreg[r];
    }
  };

  // prologue: stage Q into PsQ region, prefetch tile 0
#pragma unroll
  for (int r = 0; r < 2; ++r) {
    int c = r * 256 + tid;
    uint4 v = *(const uint4*)(qkv + (size_t)(q0 + (c >> 3)) * 3072 + h * 64 + (c & 7) * 8);
    *(uint4*)(&PsQ[(c >> 3) * LQ + (c & 7) * 8]) = v;
  }
  load_tile(kt0);
  __syncthreads();
  bf16x8 qa[2];
#pragma unroll
  for (int kq = 0; kq < 2; ++kq)
    qa[kq] = *(const bf16x8*)(&PsQ[(w * 16 + (l & 15)) * LQ + kq * 32 + (l >> 4) * 8]);
  // No extra barrier: first Ps write happens after iter-0 mid-barrier, by which
  // point every wave has read its qa (program order before its store_tile).
  u16* Ps = PsQ + w * 16 * LP;

  f32x4 oacc[4] = {};
  float mi[4], li[4];
#pragma unroll
  for (int r = 0; r < 4; ++r) { mi[r] = -1e30f; li[r] = 0.f; }

  for (int it = 0; it < 8; ++it) {
    store_tile();
    __syncthreads();                       // LDS tile valid for all waves
    if (it < 7) load_tile(kt0 + (it + 1) * 128);  // prefetch overlaps compute

    // S = Q K^T  (16 q-rows x 128 keys per wave)
    f32x4 s[8];
#pragma unroll
    for (int n = 0; n < 8; ++n) {
      f32x4 zz = {};
      bf16x8 kb0 = *(const bf16x8*)(&Ks[(n * 16 + (l & 15)) * LQ + (l >> 4) * 8]);
      bf16x8 kb1 = *(const bf16x8*)(&Ks[(n * 16 + (l & 15)) * LQ + 32 + (l >> 4) * 8]);
      zz = __builtin_amdgcn_mfma_f32_16x16x32_bf16(qa[0], kb0, zz, 0, 0, 0);
      zz = __builtin_amdgcn_mfma_f32_16x16x32_bf16(qa[1], kb1, zz, 0, 0, 0);
      s[n] = zz;
    }
    // online softmax
    float alpha[4];
#pragma unroll
    for (int r = 0; r < 4; ++r) {
      float m = -1e30f;
#pragma unroll
      for (int n = 0; n < 8; ++n) m = fmaxf(m, s[n][r]);
#pragma unroll
      for (int d = 1; d < 16; d <<= 1) m = fmaxf(m, __shfl_xor(m, d));
      m *= 0.125f;
      float mn = fmaxf(mi[r], m);
      alpha[r] = __expf(mi[r] - mn);
      mi[r] = mn;
      li[r] *= alpha[r];
    }
#pragma unroll
    for (int n = 0; n < 4; ++n)
#pragma unroll
      for (int r = 0; r < 4; ++r) oacc[n][r] *= alpha[r];
    float rs[4] = {0.f, 0.f, 0.f, 0.f};
#pragma unroll
    for (int n = 0; n < 8; ++n)
#pragma unroll
      for (int r = 0; r < 4; ++r) {
        float pv = __expf(s[n][r] * 0.125f - mi[r]);
        rs[r] += pv;
        Ps[((l >> 4) * 4 + r) * LP + n * 16 + (l & 15)] = f2b(pv);
      }
#pragma unroll
    for (int r = 0; r < 4; ++r) {
      float t = rs[r];
#pragma unroll
      for (int d = 1; d < 16; d <<= 1) t += __shfl_xor(t, d);
      li[r] += t;
    }
    // O += P V
    bf16x8 pa[4];
#pragma unroll
    for (int ks = 0; ks < 4; ++ks)
      pa[ks] = *(const bf16x8*)(&Ps[(l & 15) * LP + ks * 32 + (l >> 4) * 8]);
#pragma unroll
    for (int n = 0; n < 4; ++n)
#pragma unroll
      for (int ks = 0; ks < 4; ++ks) {
        bf16x8 vb = *(const bf16x8*)(&Vs[(n * 16 + (l & 15)) * LV + ks * 32 + (l >> 4) * 8]);
        oacc[n] = __builtin_amdgcn_mfma_f32_16x16x32_bf16(pa[ks], vb, oacc[n], 0, 0, 0);
      }
    __syncthreads();                       // all reads done before next store_tile
  }

  // epilogue: unnormalized O (fp32) + (m,l)
#pragma unroll
  for (int r = 0; r < 4; ++r) {
    const int srow = q0 + w * 16 + (l >> 4) * 4 + r;
    const size_t rowIdx = (size_t)(z * kH + h) * kS + srow;
    if ((l & 15) == 0) { Ml[rowIdx * 2] = mi[r]; Ml[rowIdx * 2 + 1] = li[r]; }
#pragma unroll
    for (int n = 0; n < 4; ++n)
      Op[rowIdx * kDK + n * 16 + (l & 15)] = oacc[n][r];
  }
}

// ---- combine 2 KV-splits: og = (w0*O0 + w1*O1) / (w0*l0 + w1*l1), bf16 ----
__global__ __launch_bounds__(256)
void flash_combine(const float* __restrict__ Op, const float* __restrict__ Ml,
                   u16* __restrict__ og) {
  constexpr size_t HS = (size_t)kH * kS;
  constexpr size_t ZO = HS * kDK;
  const int t = blockIdx.x * 256 + threadIdx.x;
  const int d4 = (t & 15) * 4;
  const size_t row = (size_t)(t >> 4);
  const float m0 = Ml[row * 2], l0 = Ml[row * 2 + 1];
  const float m1 = Ml[(HS + row) * 2], l1 = Ml[(HS + row) * 2 + 1];
  const float m = fmaxf(m0, m1);
  const float w0 = __expf(m0 - m), w1 = __expf(m1 - m);
  const float inv = 1.f / (w0 * l0 + w1 * l1);
  const float4 a = *(const float4*)(Op + row * kDK + d4);
  const float4 b = *(const float4*)(Op + ZO + row * kDK + d4);
  ushort4 o;
  o.x = f2b((w0 * a.x + w1 * b.x) * inv);
  o.y = f2b((w0 * a.y + w1 * b.y) * inv);
  o.z = f2b((w0 * a.z + w1 * b.z) * inv);
  o.w = f2b((w0 * a.w + w1 * b.w) * inv);
  *(ushort4*)(og + row * kDK + d4) = o;
}

extern "C" void kernel_launch(void* const* d_in, const int* in_sizes, int n_in,
                              void* d_out, int out_size, void* d_ws, size_t ws_size,
                              hipStream_t stream) {
  const float* x = (const float*)d_in[0];
  const float* wq = (const float*)d_in[1];
  const float* bq = (const float*)d_in[2];
  const float* wk = (const float*)d_in[3];
  const float* bk = (const float*)d_in[4];
  const float* wv = (const float*)d_in[5];
  const float* bv = (const float*)d_in[6];
  const float* wo = (const float*)d_in[7];
  const float* bo = (const float*)d_in[8];
  const float* w1 = (const float*)d_in[9];
  const float* b1 = (const float*)d_in[10];
  const float* w2 = (const float*)d_in[11];
  const float* b2 = (const float*)d_in[12];
  const float* ln1g = (const float*)d_in[13];
  const float* ln1b = (const float*)d_in[14];
  const float* ln2g = (const float*)d_in[15];
  const float* ln2b = (const float*)d_in[16];
  float* out = (float*)d_out;

  // Workspace plan:
  //   pool:  h1 wqkvt qkv vt og wot h2 w1t bqkv | x2 fbuf w2t
  //   split-K GEMM partials alias pool base (those buffers dead by then)
  //   flash Op/Ml (17.3MB) alias [x2..fbuf) — both written only after combine
  char* p = (char*)d_ws;
  auto alloc = [&](size_t bytes) { void* q = (void*)p; p += (bytes + 255) & ~(size_t)255; return q; };
  u16* h1 = (u16*)alloc((size_t)kS * kD * 2);
  u16* wqkvt = (u16*)alloc((size_t)3 * kD * kD * 2);
  u16* qkv = (u16*)alloc((size_t)kS * 3 * kD * 2);
  u16* vt = (u16*)alloc((size_t)kH * kDK * kS * 2);
  u16* og = (u16*)alloc((size_t)kS * kD * 2);
  u16* wot = (u16*)alloc((size_t)kD * kD * 2);
  u16* h2 = (u16*)alloc((size_t)kS * kD * 2);
  u16* w1t = (u16*)alloc((size_t)kD * kMLP * 2);
  float* bqkv = (float*)alloc((size_t)3 * kD * 4);
  float* x2 = (float*)alloc((size_t)kS * kD * 4);
  u16* fbuf = (u16*)alloc((size_t)kS * kMLP * 2);
  u16* w2t = (u16*)alloc((size_t)kMLP * kD * 2);
  float* part = (float*)d_ws;              // split-K partials alias pool base
  float* Op = x2;                          // flash partials alias x2+fbuf region
  float* Ml = Op + (size_t)2 * kH * kS * kDK;
  const size_t strideMN = (size_t)kS * kD;

  dim3 tb(32, 8);
  transpose_cvt<<<dim3(kD / 32, kD / 32), tb, 0, stream>>>(wq, wqkvt, kD, kD);
  transpose_cvt<<<dim3(kD / 32, kD / 32), tb, 0, stream>>>(wk, wqkvt + kD * kD, kD, kD);
  transpose_cvt<<<dim3(kD / 32, kD / 32), tb, 0, stream>>>(wv, wqkvt + 2 * kD * kD, kD, kD);
  transpose_cvt<<<dim3(kD / 32, kD / 32), tb, 0, stream>>>(wo, wot, kD, kD);
  transpose_cvt<<<dim3(kMLP / 32, kD / 32), tb, 0, stream>>>(w1, w1t, kD, kMLP);
  transpose_cvt<<<dim3(kD / 32, kMLP / 32), tb, 0, stream>>>(w2, w2t, kMLP, kD);
  concat_bias<<<dim3(12), dim3(256), 0, stream>>>(bq, bk, bv, bqkv);

  ln_kernel<<<dim3(kS), dim3(256), 0, stream>>>(x, ln1g, ln1b, h1);
  gemm_bt<0><<<dim3(3 * kD / 128, kS / 128, 1), dim3(256), 0, stream>>>(
      h1, wqkvt, bqkv, qkv, 3 * kD, kD, kD);
  vtrans<<<dim3(kS / 64, kH), dim3(256), 0, stream>>>(qkv, vt);
  flash_attn<<<dim3(kS / 64, kH, 2), dim3(256), 0, stream>>>(qkv, vt, Op, Ml);
  flash_combine<<<dim3(kH * kS * 16 / 256), dim3(256), 0, stream>>>(Op, Ml, og);
  gemm_bt<3><<<dim3(kD / 128, kS / 128, 2), dim3(256), 0, stream>>>(
      og, wot, nullptr, part, kD, kD, kD / 2);
  reduce_add<2><<<dim3(kS * kD / 4 / 256), dim3(256), 0, stream>>>(
      part, bo, x, x2, kD, strideMN);
  ln_kernel<<<dim3(kS), dim3(256), 0, stream>>>(x2, ln2g, ln2b, h2);
  gemm_bt<1><<<dim3(kMLP / 128, kS / 128, 1), dim3(256), 0, stream>>>(
      h2, w1t, b1, fbuf, kMLP, kD, kD);
  gemm_bt<3><<<dim3(kD / 128, kS / 128, 4), dim3(256), 0, stream>>>(
      fbuf, w2t, nullptr, part, kD, kMLP, kMLP / 4);
  reduce_add<4><<<dim3(kS * kD / 4 / 256), dim3(256), 0, stream>>>(
      part, b2, x2, out, kD, strideMN);
}

// Round 4
// 332.198 us; speedup vs baseline: 1.1104x; 1.1104x over previous
//
#include <hip/hip_runtime.h>

// EncoderBlock: pre-LN MHSA + pre-LN GELU FFN.  S=2048 D=1024 H=16 DK=64 MLP=4096.
// GEMMs: bf16 MFMA 16x16x32, 128x128 tile, XOR-swizzled LDS, split-K for N=1024.
// Attention: flash, KV-split x2, async16 (global_load_lds) staging into linear
// XOR-swizzled LDS (no padded strides; DMA writes burst-linear -> no 8-way write
// conflicts; swizzled b128 reads are 2-way = free).  No tight launch_bounds:
// round-3 showed (256,3)+prefetch regs spills 230MB to scratch.

constexpr int kS = 2048, kD = 1024, kH = 16, kDK = 64, kMLP = 4096;
constexpr float kEps = 1e-5f;

using u16 = unsigned short;
using u32 = unsigned int;
typedef float f32x4 __attribute__((ext_vector_type(4)));
typedef short bf16x8 __attribute__((ext_vector_type(8)));   // 8 bf16 = 4 VGPRs

__device__ __forceinline__ u16 f2b(float f) {               // fp32 -> bf16 (RNE)
  u32 u = __builtin_bit_cast(u32, f);
  return (u16)((u + 0x7fffu + ((u >> 16) & 1u)) >> 16);
}

typedef const __attribute__((address_space(1))) u32* gas1;
typedef __attribute__((address_space(3))) u32* las3;
__device__ __forceinline__ void async16(const void* g, void* l) {
  __builtin_amdgcn_global_load_lds((gas1)g, (las3)l, 16, 0, 0);
}

// ---------------- LayerNorm: fp32 [row][1024] -> bf16 ----------------
__global__ __launch_bounds__(256)
void ln_kernel(const float* __restrict__ x, const float* __restrict__ g,
               const float* __restrict__ b, u16* __restrict__ out) {
  __shared__ float red[8];
  const int row = blockIdx.x, tid = threadIdx.x;
  const float4 v = *(const float4*)(x + (size_t)row * kD + tid * 4);
  float s = v.x + v.y + v.z + v.w;
  float ss = v.x * v.x + v.y * v.y + v.z * v.z + v.w * v.w;
#pragma unroll
  for (int d = 1; d < 64; d <<= 1) { s += __shfl_xor(s, d); ss += __shfl_xor(ss, d); }
  if ((tid & 63) == 0) { red[tid >> 6] = s; red[4 + (tid >> 6)] = ss; }
  __syncthreads();
  const float m = (red[0] + red[1] + red[2] + red[3]) * (1.f / kD);
  const float var = (red[4] + red[5] + red[6] + red[7]) * (1.f / kD) - m * m;
  const float r = rsqrtf(var + kEps);
  const float4 gv = *(const float4*)(g + tid * 4);
  const float4 bv = *(const float4*)(b + tid * 4);
  ushort4 o;
  o.x = f2b((v.x - m) * r * gv.x + bv.x);
  o.y = f2b((v.y - m) * r * gv.y + bv.y);
  o.z = f2b((v.z - m) * r * gv.z + bv.z);
  o.w = f2b((v.w - m) * r * gv.w + bv.w);
  *(ushort4*)(out + (size_t)row * kD + tid * 4) = o;
}

// ------------- transpose + fp32->bf16:  out[c][r] = in[r][c] -------------
__global__ __launch_bounds__(256)
void transpose_cvt(const float* __restrict__ in, u16* __restrict__ out, int R, int C) {
  __shared__ float tile[32][33];
  const int c0 = blockIdx.x * 32, r0 = blockIdx.y * 32;
  const int x = threadIdx.x, y = threadIdx.y;
#pragma unroll
  for (int i = 0; i < 4; ++i)
    tile[y + i * 8][x] = in[(size_t)(r0 + y + i * 8) * C + c0 + x];
  __syncthreads();
#pragma unroll
  for (int i = 0; i < 4; ++i)
    out[(size_t)(c0 + y + i * 8) * R + r0 + x] = f2b(tile[x][y + i * 8]);
}

__global__ void concat_bias(const float* __restrict__ bq, const float* __restrict__ bk,
                            const float* __restrict__ bv, float* __restrict__ out) {
  int i = blockIdx.x * 256 + threadIdx.x;  // 3072
  out[i] = i < kD ? bq[i] : (i < 2 * kD ? bk[i - kD] : bv[i - 2 * kD]);
}

// --- per-head V transpose: qkv[s][2048+h*64+d] (bf16) -> vt[h][d][s] (bf16) ---
__global__ __launch_bounds__(256)
void vtrans(const u16* __restrict__ qkv, u16* __restrict__ vt) {
  __shared__ u16 t[64][72];
  const int s0 = blockIdx.x * 64, h = blockIdx.y, tid = threadIdx.x;
#pragma unroll
  for (int r = 0; r < 2; ++r) {
    int chunk = r * 256 + tid, row = chunk >> 3, col = (chunk & 7) * 8;
    uint4 v = *(const uint4*)(qkv + (size_t)(s0 + row) * 3072 + 2 * kD + h * 64 + col);
    *(uint4*)(&t[row][col]) = v;
  }
  __syncthreads();
#pragma unroll
  for (int r = 0; r < 2; ++r) {
    int chunk = r * 256 + tid, drow = chunk >> 3, scol = (chunk & 7) * 8;
    u16 tmp[8];
#pragma unroll
    for (int j = 0; j < 8; ++j) tmp[j] = t[scol + j][drow];
    *(uint4*)(vt + (size_t)h * 64 * kS + (size_t)drow * kS + s0 + scol) = *(uint4*)tmp;
  }
}

// ---------------- bt-GEMM: C[M,N] = A[M,K](bf16) x Bt[N,K](bf16) ----------------
// EPI 0: bf16 out (+bias)  EPI 1: bf16 gelu_erf out (+bias)  EPI 3: fp32 split-K partial
template <int EPI>
__global__ __launch_bounds__(256, 2)
void gemm_bt(const u16* __restrict__ A, const u16* __restrict__ Bt,
             const float* __restrict__ bias, void* __restrict__ Cout,
             int N, int K, int Ksub) {
  constexpr int BM = 128, BN = 128, BK = 32;
  constexpr int MT = 4, NT = 4;
  __shared__ u16 As[BM * BK];
  __shared__ u16 Bs[BN * BK];
  const int tid = threadIdx.x;
  const int w = tid >> 6, l = tid & 63;
  const int wm = w >> 1, wn = w & 1;
  const int row0 = blockIdx.y * BM, col0 = blockIdx.x * BN;
  const int koff = blockIdx.z * Ksub;

  const int sc = ((l & 3) ^ ((l >> 3) & 3)) * 8;   // XOR-swizzled staging chunk
  const u16* Ag = A + (size_t)(row0 + w * 16 + (l >> 2)) * K + koff + sc;
  const u16* Bg = Bt + (size_t)(col0 + w * 16 + (l >> 2)) * K + koff + sc;
  u16* AsW = As + w * 512;
  u16* BsW = Bs + w * 512;

  f32x4 acc[MT][NT] = {};
  const int q = l >> 4;

  for (int kt = 0; kt < Ksub; kt += BK) {
#pragma unroll
    for (int r = 0; r < 2; ++r) async16(Ag + (size_t)r * 64 * K + kt, AsW + r * 2048);
#pragma unroll
    for (int r = 0; r < 2; ++r) async16(Bg + (size_t)r * 64 * K + kt, BsW + r * 2048);
    __syncthreads();
    bf16x8 af[MT], bfr[NT];
#pragma unroll
    for (int i = 0; i < MT; ++i) {
      const int ra = wm * 64 + i * 16 + (l & 15);
      af[i] = *(const bf16x8*)(As + ra * 32 + (q ^ ((ra >> 1) & 3)) * 8);
    }
#pragma unroll
    for (int j = 0; j < NT; ++j) {
      const int rb = wn * 64 + j * 16 + (l & 15);
      bfr[j] = *(const bf16x8*)(Bs + rb * 32 + (q ^ ((rb >> 1) & 3)) * 8);
    }
#pragma unroll
    for (int i = 0; i < MT; ++i)
#pragma unroll
      for (int j = 0; j < NT; ++j)
        acc[i][j] = __builtin_amdgcn_mfma_f32_16x16x32_bf16(af[i], bfr[j], acc[i][j], 0, 0, 0);
    __syncthreads();
  }

  float* Pf = nullptr;
  if constexpr (EPI == 3)
    Pf = (float*)Cout + (size_t)blockIdx.z * gridDim.y * BM * N;
#pragma unroll
  for (int i = 0; i < MT; ++i) {
    const int row = row0 + wm * 64 + i * 16 + ((l >> 4) << 2);
#pragma unroll
    for (int j = 0; j < NT; ++j) {
      const int col = col0 + wn * 64 + j * 16 + (l & 15);
      float bb = 0.f;
      if constexpr (EPI != 3) bb = bias[col];
#pragma unroll
      for (int r = 0; r < 4; ++r) {
        const size_t idx = (size_t)(row + r) * N + col;
        float v = acc[i][j][r] + bb;
        if constexpr (EPI == 0) {
          ((u16*)Cout)[idx] = f2b(v);
        } else if constexpr (EPI == 1) {
          ((u16*)Cout)[idx] = f2b(0.5f * v * (1.f + erff(v * 0.7071067811865475f)));
        } else {
          Pf[idx] = v;
        }
      }
    }
  }
}

// ---- split-K reduce: out = sum_s parts[s] + bias + res  (fp32, float4) ----
template <int KS>
__global__ __launch_bounds__(256)
void reduce_add(const float* __restrict__ parts, const float* __restrict__ bias,
                const float* __restrict__ res, float* __restrict__ out,
                int N, size_t strideMN) {
  const size_t b = ((size_t)blockIdx.x * 256 + threadIdx.x) * 4;
  float4 a = *(const float4*)(res + b);
  const float4 bv = *(const float4*)(bias + (b & (size_t)(N - 1)));
  a.x += bv.x; a.y += bv.y; a.z += bv.z; a.w += bv.w;
#pragma unroll
  for (int s = 0; s < KS; ++s) {
    const float4 p = *(const float4*)(parts + s * strideMN + b);
    a.x += p.x; a.y += p.y; a.z += p.z; a.w += p.w;
  }
  *(float4*)(out + b) = a;
}

// ---------------- flash attention (KV-split x2, async16 staging) ----------------
// grid (S/64, H, 2); 4 waves; wave w owns q-rows [q0+w*16,+16).  Each block does
// 8 K-tiles of 128 keys.  Outputs UNNORMALIZED O (fp32) + (m,l) per row.
// LDS layouts are LINEAR (DMA-compatible); chunk slots XOR-swizzled by row:
// slot s of row r holds global 16B-chunk (s ^ (r&7)).
__global__ __launch_bounds__(256)
void flash_attn(const u16* __restrict__ qkv, const u16* __restrict__ vt,
                float* __restrict__ Op, float* __restrict__ Ml) {
  constexpr int LP = 140;            // Ps row stride (u16)
  __shared__ u16 PsQ[4 * 16 * LP];   // Ps per-wave; Q[64][64] linear in first 8KB (prologue)
  __shared__ u16 Ks[128 * 64];       // [key][dk] linear, swizzled chunks
  __shared__ u16 Vs[64 * 128];       // [dk][key] linear, swizzled chunks
  const int tid = threadIdx.x, w = tid >> 6, l = tid & 63;
  const int h = blockIdx.y, q0 = blockIdx.x * 64, z = blockIdx.z;
  const int kt0 = z * (kS / 2);
  const int q = l >> 4;

  const u16* Qg = qkv + h * 64;
  const u16* Kg = qkv + kD + h * 64;
  const u16* Vg = vt + (size_t)h * 64 * kS;

  // --- prologue: stage Q via DMA (2 passes; 8 rows/wave-pass), swizzled
  {
    const int r8 = l >> 3, c = (l & 7) ^ r8;
#pragma unroll
    for (int p = 0; p < 2; ++p) {
      const int row = (p * 4 + w) * 8 + r8;
      async16(Qg + (size_t)(q0 + row) * 3072 + c * 8, PsQ + (p * 4 + w) * 512);
    }
  }
  __syncthreads();                    // vmcnt drained -> Q valid
  bf16x8 qa[2];
  const int rq = w * 16 + (l & 15);
#pragma unroll
  for (int kq = 0; kq < 2; ++kq)
    qa[kq] = *(const bf16x8*)(PsQ + rq * 64 + ((kq * 4 + q) ^ (l & 7)) * 8);
  u16* Ps = PsQ + w * 16 * LP;
  // qa reads complete before each wave's first barrier (compiler drains lgkmcnt),
  // so Ps writes (post barrier-2 of iter 0) can't race the Q reads.

  f32x4 oacc[4] = {};
  float mi[4], li[4];
#pragma unroll
  for (int r = 0; r < 4; ++r) { mi[r] = -1e30f; li[r] = 0.f; }

  for (int it = 0; it < 8; ++it) {
    __syncthreads();                  // all waves done reading prev K/V tile
    const int kt = kt0 + it * 128;
    {   // K tile [128][64]: 4 passes, 8 rows/wave-pass
      const int r8 = l >> 3, c = (l & 7) ^ r8;
#pragma unroll
      for (int p = 0; p < 4; ++p) {
        const int row = (p * 4 + w) * 8 + r8;
        async16(Kg + (size_t)(kt + row) * 3072 + c * 8, Ks + (p * 4 + w) * 512);
      }
    }
    {   // V^T tile [64][128]: 4 passes, 4 rows/wave-pass (16 chunks/row)
#pragma unroll
      for (int p = 0; p < 4; ++p) {
        const int row = (p * 4 + w) * 4 + (l >> 4);
        const int c = (l & 15) ^ (row & 7);
        async16(Vg + (size_t)row * kS + kt + c * 8, Vs + (p * 4 + w) * 512);
      }
    }
    __syncthreads();                  // vmcnt drained -> tile valid

    // S = Q K^T  (16 q-rows x 128 keys per wave)
    f32x4 s[8];
#pragma unroll
    for (int n = 0; n < 8; ++n) {
      const int rk = n * 16 + (l & 15);
      f32x4 zz = {};
      bf16x8 kb0 = *(const bf16x8*)(Ks + rk * 64 + ((0 + q) ^ (rk & 7)) * 8);
      bf16x8 kb1 = *(const bf16x8*)(Ks + rk * 64 + ((4 + q) ^ (rk & 7)) * 8);
      zz = __builtin_amdgcn_mfma_f32_16x16x32_bf16(qa[0], kb0, zz, 0, 0, 0);
      zz = __builtin_amdgcn_mfma_f32_16x16x32_bf16(qa[1], kb1, zz, 0, 0, 0);
      s[n] = zz;
    }
    // online softmax
    float alpha[4];
#pragma unroll
    for (int r = 0; r < 4; ++r) {
      float m = -1e30f;
#pragma unroll
      for (int n = 0; n < 8; ++n) m = fmaxf(m, s[n][r]);
#pragma unroll
      for (int d = 1; d < 16; d <<= 1) m = fmaxf(m, __shfl_xor(m, d));
      m *= 0.125f;
      float mn = fmaxf(mi[r], m);
      alpha[r] = __expf(mi[r] - mn);
      mi[r] = mn;
      li[r] *= alpha[r];
    }
#pragma unroll
    for (int n = 0; n < 4; ++n)
#pragma unroll
      for (int r = 0; r < 4; ++r) oacc[n][r] *= alpha[r];
    float rs[4] = {0.f, 0.f, 0.f, 0.f};
#pragma unroll
    for (int n = 0; n < 8; ++n)
#pragma unroll
      for (int r = 0; r < 4; ++r) {
        float pv = __expf(s[n][r] * 0.125f - mi[r]);
        rs[r] += pv;
        Ps[((l >> 4) * 4 + r) * LP + n * 16 + (l & 15)] = f2b(pv);
      }
#pragma unroll
    for (int r = 0; r < 4; ++r) {
      float t = rs[r];
#pragma unroll
      for (int d = 1; d < 16; d <<= 1) t += __shfl_xor(t, d);
      li[r] += t;
    }
    // O += P V
    bf16x8 pa[4];
#pragma unroll
    for (int ks = 0; ks < 4; ++ks)
      pa[ks] = *(const bf16x8*)(&Ps[(l & 15) * LP + ks * 32 + q * 8]);
#pragma unroll
    for (int n = 0; n < 4; ++n) {
      const int rv = n * 16 + (l & 15);
#pragma unroll
      for (int ks = 0; ks < 4; ++ks) {
        bf16x8 vb = *(const bf16x8*)(Vs + rv * 128 + ((ks * 4 + q) ^ (rv & 7)) * 8);
        oacc[n] = __builtin_amdgcn_mfma_f32_16x16x32_bf16(pa[ks], vb, oacc[n], 0, 0, 0);
      }
    }
  }

  // epilogue: unnormalized O (fp32) + (m,l)
#pragma unroll
  for (int r = 0; r < 4; ++r) {
    const int srow = q0 + w * 16 + (l >> 4) * 4 + r;
    const size_t rowIdx = (size_t)(z * kH + h) * kS + srow;
    if ((l & 15) == 0) { Ml[rowIdx * 2] = mi[r]; Ml[rowIdx * 2 + 1] = li[r]; }
#pragma unroll
    for (int n = 0; n < 4; ++n)
      Op[rowIdx * kDK + n * 16 + (l & 15)] = oacc[n][r];
  }
}

// ---- combine 2 KV-splits: og = (w0*O0 + w1*O1) / (w0*l0 + w1*l1), bf16 ----
__global__ __launch_bounds__(256)
void flash_combine(const float* __restrict__ Op, const float* __restrict__ Ml,
                   u16* __restrict__ og) {
  constexpr size_t HS = (size_t)kH * kS;
  constexpr size_t ZO = HS * kDK;
  const int t = blockIdx.x * 256 + threadIdx.x;
  const int d4 = (t & 15) * 4;
  const size_t row = (size_t)(t >> 4);
  const float m0 = Ml[row * 2], l0 = Ml[row * 2 + 1];
  const float m1 = Ml[(HS + row) * 2], l1 = Ml[(HS + row) * 2 + 1];
  const float m = fmaxf(m0, m1);
  const float w0 = __expf(m0 - m), w1 = __expf(m1 - m);
  const float inv = 1.f / (w0 * l0 + w1 * l1);
  const float4 a = *(const float4*)(Op + row * kDK + d4);
  const float4 b = *(const float4*)(Op + ZO + row * kDK + d4);
  ushort4 o;
  o.x = f2b((w0 * a.x + w1 * b.x) * inv);
  o.y = f2b((w0 * a.y + w1 * b.y) * inv);
  o.z = f2b((w0 * a.z + w1 * b.z) * inv);
  o.w = f2b((w0 * a.w + w1 * b.w) * inv);
  *(ushort4*)(og + row * kDK + d4) = o;
}

extern "C" void kernel_launch(void* const* d_in, const int* in_sizes, int n_in,
                              void* d_out, int out_size, void* d_ws, size_t ws_size,
                              hipStream_t stream) {
  const float* x = (const float*)d_in[0];
  const float* wq = (const float*)d_in[1];
  const float* bq = (const float*)d_in[2];
  const float* wk = (const float*)d_in[3];
  const float* bk = (const float*)d_in[4];
  const float* wv = (const float*)d_in[5];
  const float* bv = (const float*)d_in[6];
  const float* wo = (const float*)d_in[7];
  const float* bo = (const float*)d_in[8];
  const float* w1 = (const float*)d_in[9];
  const float* b1 = (const float*)d_in[10];
  const float* w2 = (const float*)d_in[11];
  const float* b2 = (const float*)d_in[12];
  const float* ln1g = (const float*)d_in[13];
  const float* ln1b = (const float*)d_in[14];
  const float* ln2g = (const float*)d_in[15];
  const float* ln2b = (const float*)d_in[16];
  float* out = (float*)d_out;

  // Workspace plan:
  //   pool:  h1 wqkvt qkv vt og wot h2 w1t bqkv | x2 fbuf w2t
  //   split-K GEMM partials alias pool base (those buffers dead by then)
  //   flash Op/Ml (17.3MB) alias [x2..fbuf) — both written only after combine
  char* p = (char*)d_ws;
  auto alloc = [&](size_t bytes) { void* q = (void*)p; p += (bytes + 255) & ~(size_t)255; return q; };
  u16* h1 = (u16*)alloc((size_t)kS * kD * 2);
  u16* wqkvt = (u16*)alloc((size_t)3 * kD * kD * 2);
  u16* qkv = (u16*)alloc((size_t)kS * 3 * kD * 2);
  u16* vt = (u16*)alloc((size_t)kH * kDK * kS * 2);
  u16* og = (u16*)alloc((size_t)kS * kD * 2);
  u16* wot = (u16*)alloc((size_t)kD * kD * 2);
  u16* h2 = (u16*)alloc((size_t)kS * kD * 2);
  u16* w1t = (u16*)alloc((size_t)kD * kMLP * 2);
  float* bqkv = (float*)alloc((size_t)3 * kD * 4);
  float* x2 = (float*)alloc((size_t)kS * kD * 4);
  u16* fbuf = (u16*)alloc((size_t)kS * kMLP * 2);
  u16* w2t = (u16*)alloc((size_t)kMLP * kD * 2);
  float* part = (float*)d_ws;              // split-K partials alias pool base
  float* Op = x2;                          // flash partials alias x2+fbuf region
  float* Ml = Op + (size_t)2 * kH * kS * kDK;
  const size_t strideMN = (size_t)kS * kD;

  dim3 tb(32, 8);
  transpose_cvt<<<dim3(kD / 32, kD / 32), tb, 0, stream>>>(wq, wqkvt, kD, kD);
  transpose_cvt<<<dim3(kD / 32, kD / 32), tb, 0, stream>>>(wk, wqkvt + kD * kD, kD, kD);
  transpose_cvt<<<dim3(kD / 32, kD / 32), tb, 0, stream>>>(wv, wqkvt + 2 * kD * kD, kD, kD);
  transpose_cvt<<<dim3(kD / 32, kD / 32), tb, 0, stream>>>(wo, wot, kD, kD);
  transpose_cvt<<<dim3(kMLP / 32, kD / 32), tb, 0, stream>>>(w1, w1t, kD, kMLP);
  transpose_cvt<<<dim3(kD / 32, kMLP / 32), tb, 0, stream>>>(w2, w2t, kMLP, kD);
  concat_bias<<<dim3(12), dim3(256), 0, stream>>>(bq, bk, bv, bqkv);

  ln_kernel<<<dim3(kS), dim3(256), 0, stream>>>(x, ln1g, ln1b, h1);
  gemm_bt<0><<<dim3(3 * kD / 128, kS / 128, 1), dim3(256), 0, stream>>>(
      h1, wqkvt, bqkv, qkv, 3 * kD, kD, kD);
  vtrans<<<dim3(kS / 64, kH), dim3(256), 0, stream>>>(qkv, vt);
  flash_attn<<<dim3(kS / 64, kH, 2), dim3(256), 0, stream>>>(qkv, vt, Op, Ml);
  flash_combine<<<dim3(kH * kS * 16 / 256), dim3(256), 0, stream>>>(Op, Ml, og);
  gemm_bt<3><<<dim3(kD / 128, kS / 128, 2), dim3(256), 0, stream>>>(
      og, wot, nullptr, part, kD, kD, kD / 2);
  reduce_add<2><<<dim3(kS * kD / 4 / 256), dim3(256), 0, stream>>>(
      part, bo, x, x2, kD, strideMN);
  ln_kernel<<<dim3(kS), dim3(256), 0, stream>>>(x2, ln2g, ln2b, h2);
  gemm_bt<1><<<dim3(kMLP / 128, kS / 128, 1), dim3(256), 0, stream>>>(
      h2, w1t, b1, fbuf, kMLP, kD, kD);
  gemm_bt<3><<<dim3(kD / 128, kS / 128, 4), dim3(256), 0, stream>>>(
      fbuf, w2t, nullptr, part, kD, kMLP, kMLP / 4);
  reduce_add<4><<<dim3(kS * kD / 4 / 256), dim3(256), 0, stream>>>(
      part, b2, x2, out, kD, strideMN);
}